// Round 10
// baseline (333.945 us; speedup 1.0000x reference)
//
#include <hip/hip_runtime.h>
#include <cstdint>

#define B_  64
#define P_  196
#define C_  768
#define HS_ 384
#define M_  49152
#define RT_ 64            // r-columns per block (2 rt of 32)
#define NB_ (M_ / RT_)    // 768 blocks = 3 clean rounds at 1 block/CU

// K-chunk = 16 scalars -> 8 rbf tiles (k16) + 1 silu tile per chunk.
#define NC1 13
#define KT1 111
#define NT1 12
#define NC2 24
#define KT2 216
#define NT2 7

#define W1P_ELEMS ((size_t)KT1 * NT1 * 512) // 681,984
#define W2P_ELEMS ((size_t)KT2 * NT2 * 512) // 774,144
#define PACK_G1   (W1P_ELEMS / 8)
#define PACK_G    ((W1P_ELEMS + W2P_ELEMS) / 8)

typedef __attribute__((ext_vector_type(8)))  short short8;
typedef __attribute__((ext_vector_type(16))) float f32x16;

#define MFMA(w, a, c) __builtin_amdgcn_mfma_f32_32x32x16_bf16((w), (a), (c), 0, 0, 0)

static __device__ __forceinline__ float bf2f(unsigned short u) {
    union { unsigned int i; float f; } v; v.i = ((unsigned int)u) << 16; return v.f;
}
static __device__ __forceinline__ unsigned short f2bf_rne(float f) {
    union { float f; unsigned int i; } v; v.f = f;
    unsigned int r = v.i + 0x7FFFu + ((v.i >> 16) & 1u);
    return (unsigned short)(r >> 16);
}
static __device__ __forceinline__ unsigned int pack2(float a, float b) {
    unsigned int ua = __float_as_uint(a) + 0x8000u;
    unsigned int ub = __float_as_uint(b) + 0x8000u;
    return __builtin_amdgcn_perm(ub, ua, 0x07060302u);  // [a | b] (a = low ushort)
}
// 8 RBF basis: exp(-(3.5s+3.5-j)^2) = exp2(-(u_j)^2), u_j = A*s+A - j*R,
// R = sqrt(log2 e).  (R4 scalar form — proven fastest.)
static __device__ __forceinline__ short8 rbf8(float s) {
    const float Rr = 1.2011224087864498f;     // sqrt(log2 e)
    const float Aa = 4.2039284307525743f;     // 3.5 * Rr
    float t1 = __builtin_fmaf(Aa, s, Aa);
    union { short8 s8; unsigned int u[4]; } r;
#pragma unroll
    for (int q = 0; q < 4; q++) {
        float u0 = t1 - (float)(2 * q) * Rr;
        float u1 = t1 - (float)(2 * q + 1) * Rr;
        r.u[q] = pack2(__builtin_amdgcn_exp2f(-u0 * u0),
                       __builtin_amdgcn_exp2f(-u1 * u1));
    }
    return r.s8;
}
static __device__ __forceinline__ unsigned int silu2(float a, float b) {
    const float L2E = 1.4426950408889634f;
    float fa = a * __builtin_amdgcn_rcpf(1.f + __builtin_amdgcn_exp2f(-L2E * a));
    float fb = b * __builtin_amdgcn_rcpf(1.f + __builtin_amdgcn_exp2f(-L2E * b));
    return pack2(fa, fb);
}

// lgkm-only barrier: LDS writes must be cross-wave visible, but vmem loads
// to private registers stay in flight across it (no vmcnt(0) drain).
static __device__ __forceinline__ void block_sync_lds() {
    __builtin_amdgcn_sched_barrier(0);
    asm volatile("s_waitcnt lgkmcnt(0)" ::: "memory");
    __builtin_amdgcn_s_barrier();
    __builtin_amdgcn_sched_barrier(0);
}

static __device__ __forceinline__ void cvt8(const float4 a, const float4 b,
                                            unsigned short* o) {
    o[0] = f2bf_rne(a.x); o[1] = f2bf_rne(a.y); o[2] = f2bf_rne(a.z); o[3] = f2bf_rne(a.w);
    o[4] = f2bf_rne(b.x); o[5] = f2bf_rne(b.y); o[6] = f2bf_rne(b.z); o[7] = f2bf_rne(b.w);
}

// pack (R8 8-wide version): one thread per 8 consecutive packed elements.
__global__ void pack_w_kernel(const float* __restrict__ w1s,
                              const float* __restrict__ w1b,
                              const float* __restrict__ w2s,
                              const float* __restrict__ w2b,
                              unsigned short* __restrict__ w1p,
                              unsigned short* __restrict__ w2p) {
    int g = blockIdx.x * 256 + threadIdx.x;
    if (g >= PACK_G) return;
    union { short8 s8; unsigned short u[8]; } ov;
    if (g < PACK_G1) {
        int lane = g & 63;
        int lin  = g >> 6;               // tt*NT1 + nt
        int nt   = lin % NT1;
        int tt   = lin / NT1;
        int cc   = (tt < 108) ? tt / 9 : 12;
        int kk   = (tt < 108) ? tt % 9 : (tt - 108);
        int ktl  = (cc < 12) ? kk : ((kk < 2) ? kk : 8);
        int n = nt * 32 + (lane & 31);
        int khalf = lane >> 5;
        if (ktl < 8) {
            int p = cc * 16 + ktl * 2 + khalf;       // always < P_
            const float4* src = (const float4*)(w1s + (size_t)n * 1568 + (size_t)p * 8);
            cvt8(src[0], src[1], ov.u);
        } else {
            int p0 = cc * 16 + khalf * 8;
            if (p0 + 7 < P_) {
                const float4* src = (const float4*)(w1b + (size_t)n * 196 + p0);
                cvt8(src[0], src[1], ov.u);
            } else {
#pragma unroll
                for (int j = 0; j < 8; j++) {
                    int p = p0 + j;
                    float v = (p < P_) ? w1b[(size_t)n * 196 + p] : 0.f;
                    ov.u[j] = f2bf_rne(v);
                }
            }
        }
        *(short8*)&w1p[(size_t)g * 8] = ov.s8;
    } else {
        int g2 = g - PACK_G1;
        int lane = g2 & 63;
        int lin  = g2 >> 6;              // tt*NT2 + nt
        int nt   = lin % NT2;
        int tt   = lin / NT2;
        int cc   = tt / 9;
        int ktl  = tt % 9;
        int n = nt * 32 + (lane & 31);
        int khalf = lane >> 5;
        if (n < P_) {
            if (ktl < 8) {
                int s = cc * 16 + ktl * 2 + khalf;
                const float4* src = (const float4*)(w2s + (size_t)n * 3072 + (size_t)s * 8);
                cvt8(src[0], src[1], ov.u);
            } else {
                int s0 = cc * 16 + khalf * 8;
                const float4* src = (const float4*)(w2b + (size_t)n * 384 + s0);
                cvt8(src[0], src[1], ov.u);
            }
        } else {
#pragma unroll
            for (int j = 0; j < 8; j++) ov.u[j] = f2bf_rne(0.f);
        }
        *(short8*)&w2p[(size_t)g2 * 8] = ov.s8;
    }
}

// frag LDS tile: [rt 2][khalf 2][col 32][8] = 1024 ushort; 9 tiles/buf.
#define TS_L  1024
#define FB_   (9 * TS_L)   // 9216 ushort per buffer

// R9 fused kernel: 512 threads (8 waves = rtw{0,1} x ntw{0..3}), RT=64 cols,
// 1 block/CU, grid 768 (3 clean rounds). fc1 phase -> h1 slice in LDS
// (bit-identical f2bf round-trip) -> fc2 phase with produce fed from LDS.
// Eliminates 75 MB of h1t global traffic + one launch.
__global__ __launch_bounds__(512, 2)
void fused_kernel(const float* __restrict__ x,
                  const unsigned short* __restrict__ w1p,
                  const float* __restrict__ b1,
                  const unsigned short* __restrict__ w2p,
                  const float* __restrict__ b2,
                  float* __restrict__ out) {
    __shared__ __align__(16) unsigned short frag[2 * FB_];   // 36 KB
    __shared__ __align__(16) unsigned short h1s[HS_ * RT_];  // 48 KB, [s][col]
    int blk = blockIdx.x;
    int tid = threadIdx.x;
    int b   = blk / 12;
    int c0  = (blk % 12) * RT_;
    const float* xb = x + (size_t)b * (P_ * C_);

    int col = tid & 63, sc = tid >> 6;       // produce mapping: 2 scalars/thread
    int lane = tid & 63, wave = tid >> 6;
    int rtw = wave >> 2, ntw = wave & 3;
    int l31 = lane & 31, half = lane >> 5;
    int rtbase = rtw << 9;                    // rt region within a tile

    int pbase_rbf  = ((col >> 5) << 9) + (col & 31) * 8;
    int pbase_silu = 8 * TS_L + ((col >> 5) << 9) + ((sc >> 2) << 8) + (col & 31) * 8 + (sc & 3) * 2;

    // =================== fc1 phase ===================
    {
        int nt0 = ntw * 3;
        f32x16 acc[3];                        // [nt]
#pragma unroll
        for (int nt = 0; nt < 3; nt++)
#pragma unroll
            for (int i = 0; i < 16; i++) acc[nt][i] = 0.f;

        const short8* wp = (const short8*)w1p;
        short8 wbuf[2][3];
        auto wload = [&](int d, const short8* wt0, int kk) {
            const short8* wt = wt0 + (size_t)kk * (NT1 * 64);
            wbuf[d][0] = wt[0]; wbuf[d][1] = wt[64]; wbuf[d][2] = wt[128];
        };
        auto do_mfma = [&](short8 w0, short8 w1, short8 w2, short8 a) {
            acc[0] = MFMA(w0, a, acc[0]);
            acc[1] = MFMA(w1, a, acc[1]);
            acc[2] = MFMA(w2, a, acc[2]);
        };
        auto produce = [&](int fb, float v0, float v1) {
            *(short8*)&frag[fb + sc * TS_L + pbase_rbf]       = rbf8(v0);
            *(short8*)&frag[fb + sc * TS_L + 256 + pbase_rbf] = rbf8(v1);
            *(unsigned int*)&frag[fb + pbase_silu] = silu2(v0, v1);
        };
        // body(cc): consume cc; produce cc+1 (slices at kk 0-2); load cc+2 (kk 3-4).
        auto body = [&](int cc, float vP0, float vP1, float& vL0, float& vL1) {
            const short8* wt0 = wp + ((size_t)(cc * 9) * NT1 + nt0) * 64 + lane;
            wload(0, wt0, 0); wload(1, wt0, 1);
            int fbP = ((cc + 1) & 1) * FB_;
            const unsigned short* fg = &frag[(cc & 1) * FB_];
            short8 a = *(const short8*)&fg[rtbase + lane * 8];
#pragma unroll
            for (int kk = 0; kk < 9; kk++) {
                short8 na;
                if (kk < 8) na = *(const short8*)&fg[(kk + 1) * TS_L + rtbase + lane * 8];
                short8 w0 = wbuf[kk & 1][0], w1 = wbuf[kk & 1][1], w2 = wbuf[kk & 1][2];
                if (kk < 7) wload(kk & 1, wt0, kk + 2);
                if (kk == 0) {
                    *(short8*)&frag[fbP + sc * TS_L + pbase_rbf] = rbf8(vP0);
                } else if (kk == 1) {
                    *(short8*)&frag[fbP + sc * TS_L + 256 + pbase_rbf] = rbf8(vP1);
                } else if (kk == 2) {
                    *(unsigned int*)&frag[fbP + pbase_silu] = silu2(vP0, vP1);
                } else if (kk == 3) {
                    int p = (cc + 2) * 16 + sc * 2; p = (p < P_) ? p : (P_ - 1);
                    vL0 = xb[(size_t)p * C_ + c0 + col];
                } else if (kk == 4) {
                    int p = (cc + 2) * 16 + sc * 2 + 1; p = (p < P_) ? p : (P_ - 1);
                    vL1 = xb[(size_t)p * C_ + c0 + col];
                }
                do_mfma(w0, w1, w2, a);
                if (kk < 8) a = na;
            }
            block_sync_lds();
        };

        float vA0, vA1, vB0, vB1;
        {
            int p0 = sc * 2, p1 = sc * 2 + 1;
            vA0 = xb[(size_t)p0 * C_ + c0 + col];
            vA1 = xb[(size_t)p1 * C_ + c0 + col];
            vB0 = xb[(size_t)(16 + p0) * C_ + c0 + col];
            vB1 = xb[(size_t)(16 + p1) * C_ + c0 + col];
        }
        produce(0, vA0, vA1);                 // chunk 0 -> frag[0]
        block_sync_lds();

        for (int c2 = 0; c2 < 6; c2++) {      // chunks 0..11
            body(2 * c2,     vB0, vB1, vA0, vA1);
            body(2 * c2 + 1, vA0, vA1, vB0, vB1);
        }
        // tail: consume chunk 12 (tiles ktl {0,1,8}; weights linear 108..110)
        {
            const short8* wt0 = wp + ((size_t)108 * NT1 + nt0) * 64 + lane;
            wload(0, wt0, 0); wload(1, wt0, 1);
            const unsigned short* fg = &frag[0];      // chunk 12 parity 0
            short8 a0 = *(const short8*)&fg[rtbase + lane * 8];
            short8 a1 = *(const short8*)&fg[TS_L + rtbase + lane * 8];
            short8 a8 = *(const short8*)&fg[8 * TS_L + rtbase + lane * 8];
            do_mfma(wbuf[0][0], wbuf[0][1], wbuf[0][2], a0);
            wload(0, wt0, 2);
            do_mfma(wbuf[1][0], wbuf[1][1], wbuf[1][2], a1);
            do_mfma(wbuf[0][0], wbuf[0][1], wbuf[0][2], a8);
        }

        // epilogue: h1 slice -> LDS (bit-identical f2bf round-trip)
#pragma unroll
        for (int nt = 0; nt < 3; nt++) {
            int n0 = (nt0 + nt) * 32 + 4 * half;
#pragma unroll
            for (int reg = 0; reg < 16; reg++) {
                int n = n0 + (reg & 3) + 8 * (reg >> 2);
                h1s[n * RT_ + rtw * 32 + l31] = f2bf_rne(acc[nt][reg] + b1[n]);
            }
        }
        block_sync_lds();
    }

    // =================== fc2 phase ===================
    {
        int nt0 = ntw * 2;
        bool two = (ntw < 3);                 // ntw 3 owns only tile 6
        int off1 = two ? 64 : 0;
        f32x16 acc[2];
#pragma unroll
        for (int nt = 0; nt < 2; nt++)
#pragma unroll
            for (int i = 0; i < 16; i++) acc[nt][i] = 0.f;

        const short8* wp = (const short8*)w2p;
        short8 wbuf[2][2];
        auto wload = [&](int d, const short8* wt0, int kk) {
            const short8* wt = wt0 + (size_t)kk * (NT2 * 64);
            wbuf[d][0] = wt[0]; wbuf[d][1] = wt[off1];
        };
        auto do_mfma = [&](short8 w0, short8 w1, short8 a) {
            acc[0] = MFMA(w0, a, acc[0]);
            if (two) acc[1] = MFMA(w1, a, acc[1]);
        };
        // prologue: produce chunk 0 from h1s
        {
            float v0 = bf2f(h1s[(sc * 2) * RT_ + col]);
            float v1 = bf2f(h1s[(sc * 2 + 1) * RT_ + col]);
            *(short8*)&frag[sc * TS_L + pbase_rbf]       = rbf8(v0);
            *(short8*)&frag[sc * TS_L + 256 + pbase_rbf] = rbf8(v1);
            *(unsigned int*)&frag[pbase_silu] = silu2(v0, v1);
        }
        block_sync_lds();

        for (int cc = 0; cc < NC2; cc++) {
            bool doProd = (cc + 1 < NC2);
            const short8* wt0 = wp + ((size_t)(cc * 9) * NT2 + nt0) * 64 + lane;
            wload(0, wt0, 0); wload(1, wt0, 1);
            int fbP = ((cc + 1) & 1) * FB_;
            const unsigned short* fg = &frag[(cc & 1) * FB_];
            short8 a = *(const short8*)&fg[rtbase + lane * 8];
            unsigned short u0 = 0, u1 = 0;
#pragma unroll
            for (int kk = 0; kk < 9; kk++) {
                short8 na;
                if (kk < 8) na = *(const short8*)&fg[(kk + 1) * TS_L + rtbase + lane * 8];
                short8 w0 = wbuf[kk & 1][0], w1 = wbuf[kk & 1][1];
                if (kk < 7) wload(kk & 1, wt0, kk + 2);
                if (doProd) {
                    if (kk == 0) {
                        u0 = h1s[((cc + 1) * 16 + sc * 2) * RT_ + col];
                        u1 = h1s[((cc + 1) * 16 + sc * 2 + 1) * RT_ + col];
                    } else if (kk == 1) {
                        *(short8*)&frag[fbP + sc * TS_L + pbase_rbf] = rbf8(bf2f(u0));
                    } else if (kk == 2) {
                        *(short8*)&frag[fbP + sc * TS_L + 256 + pbase_rbf] = rbf8(bf2f(u1));
                    } else if (kk == 3) {
                        *(unsigned int*)&frag[fbP + pbase_silu] = silu2(bf2f(u0), bf2f(u1));
                    }
                }
                do_mfma(w0, w1, a);
                if (kk < 8) a = na;
            }
            block_sync_lds();
        }

        // epilogue: out[b,p,c] = acc + b2[p] + x[b,p,c]
#pragma unroll
        for (int nt = 0; nt < 2; nt++) {
            if (nt == 0 || two) {
                int p0 = (nt0 + nt) * 32 + 4 * half;
#pragma unroll
                for (int reg = 0; reg < 16; reg++) {
                    int p = p0 + (reg & 3) + 8 * (reg >> 2);
                    if (p < P_) {
                        size_t off = ((size_t)b * P_ + p) * C_ + c0 + rtw * 32 + l31;
                        out[off] = acc[nt][reg] + b2[p] + x[off];
                    }
                }
            }
        }
    }
}

extern "C" void kernel_launch(void* const* d_in, const int* in_sizes, int n_in,
                              void* d_out, int out_size, void* d_ws, size_t ws_size,
                              hipStream_t stream) {
    const float* x   = (const float*)d_in[0];
    const float* w1s = (const float*)d_in[1];
    const float* w1b = (const float*)d_in[2];
    const float* b1  = (const float*)d_in[3];
    const float* w2s = (const float*)d_in[4];
    const float* w2b = (const float*)d_in[5];
    const float* b2  = (const float*)d_in[6];
    float* out = (float*)d_out;

    unsigned short* w1p = (unsigned short*)d_ws;            // ~1.4 MB
    unsigned short* w2p = w1p + W1P_ELEMS;                  // ~1.5 MB

    int pack_blocks = (PACK_G + 255) / 256;                 // 711
    pack_w_kernel<<<pack_blocks, 256, 0, stream>>>(w1s, w1b, w2s, w2b, w1p, w2p);
    fused_kernel<<<NB_, 512, 0, stream>>>(x, w1p, b1, w2p, b2, out);
}

// Round 11
// 244.954 us; speedup vs baseline: 1.3633x; 1.3633x over previous
//
#include <hip/hip_runtime.h>
#include <cstdint>

#define B_  64
#define P_  196
#define C_  768
#define HS_ 384
#define M_  49152
#define RT_ 96            // r-columns per block (3 rt of 32)
#define NB_ (M_ / RT_)    // 512 blocks = exactly 2/CU

// K-chunk = 16 scalars -> 8 rbf tiles (k16) + 1 silu tile per chunk.
#define NC1 13
#define KT1 111
#define NT1 12
#define NC2 24
#define KT2 216
#define NT2 7

#define H1_ELEMS  ((size_t)M_ * HS_)
#define W1P_ELEMS ((size_t)KT1 * NT1 * 512) // 681,984
#define W2P_ELEMS ((size_t)KT2 * NT2 * 512) // 774,144
#define PACK_G1   (W1P_ELEMS / 8)
#define PACK_G    ((W1P_ELEMS + W2P_ELEMS) / 8)

typedef __attribute__((ext_vector_type(8)))  short short8;
typedef __attribute__((ext_vector_type(16))) float f32x16;

#define MFMA(w, a, c) __builtin_amdgcn_mfma_f32_32x32x16_bf16((w), (a), (c), 0, 0, 0)

static __device__ __forceinline__ float bf2f(unsigned short u) {
    union { unsigned int i; float f; } v; v.i = ((unsigned int)u) << 16; return v.f;
}
static __device__ __forceinline__ unsigned short f2bf_rne(float f) {
    union { float f; unsigned int i; } v; v.f = f;
    unsigned int r = v.i + 0x7FFFu + ((v.i >> 16) & 1u);
    return (unsigned short)(r >> 16);
}
static __device__ __forceinline__ unsigned int pack2(float a, float b) {
    unsigned int ua = __float_as_uint(a) + 0x8000u;
    unsigned int ub = __float_as_uint(b) + 0x8000u;
    return __builtin_amdgcn_perm(ub, ua, 0x07060302u);  // [a | b] (a = low ushort)
}
// 8 RBF basis: exp(-(3.5s+3.5-j)^2) = exp2(-(u_j)^2), u_j = A*s+A - j*R,
// R = sqrt(log2 e).  (R4 scalar form — proven fastest.)
static __device__ __forceinline__ short8 rbf8(float s) {
    const float Rr = 1.2011224087864498f;     // sqrt(log2 e)
    const float Aa = 4.2039284307525743f;     // 3.5 * Rr
    float t1 = __builtin_fmaf(Aa, s, Aa);
    union { short8 s8; unsigned int u[4]; } r;
#pragma unroll
    for (int q = 0; q < 4; q++) {
        float u0 = t1 - (float)(2 * q) * Rr;
        float u1 = t1 - (float)(2 * q + 1) * Rr;
        r.u[q] = pack2(__builtin_amdgcn_exp2f(-u0 * u0),
                       __builtin_amdgcn_exp2f(-u1 * u1));
    }
    return r.s8;
}
static __device__ __forceinline__ unsigned int silu2(float a, float b) {
    const float L2E = 1.4426950408889634f;
    float fa = a * __builtin_amdgcn_rcpf(1.f + __builtin_amdgcn_exp2f(-L2E * a));
    float fb = b * __builtin_amdgcn_rcpf(1.f + __builtin_amdgcn_exp2f(-L2E * b));
    return pack2(fa, fb);
}

// lgkm-only barrier: LDS writes must be cross-wave visible, but vmem loads
// to private registers stay in flight across it (no vmcnt(0) drain).
static __device__ __forceinline__ void block_sync_lds() {
    __builtin_amdgcn_sched_barrier(0);
    asm volatile("s_waitcnt lgkmcnt(0)" ::: "memory");
    __builtin_amdgcn_s_barrier();
    __builtin_amdgcn_sched_barrier(0);
}

static __device__ __forceinline__ void cvt8(const float4 a, const float4 b,
                                            unsigned short* o) {
    o[0] = f2bf_rne(a.x); o[1] = f2bf_rne(a.y); o[2] = f2bf_rne(a.z); o[3] = f2bf_rne(a.w);
    o[4] = f2bf_rne(b.x); o[5] = f2bf_rne(b.y); o[6] = f2bf_rne(b.z); o[7] = f2bf_rne(b.w);
}

// pack (R8 8-wide): one thread per 8 consecutive packed elements.
__global__ void pack_w_kernel(const float* __restrict__ w1s,
                              const float* __restrict__ w1b,
                              const float* __restrict__ w2s,
                              const float* __restrict__ w2b,
                              unsigned short* __restrict__ w1p,
                              unsigned short* __restrict__ w2p) {
    int g = blockIdx.x * 256 + threadIdx.x;
    if (g >= PACK_G) return;
    union { short8 s8; unsigned short u[8]; } ov;
    if (g < PACK_G1) {
        int lane = g & 63;
        int lin  = g >> 6;               // tt*NT1 + nt
        int nt   = lin % NT1;
        int tt   = lin / NT1;
        int cc   = (tt < 108) ? tt / 9 : 12;
        int kk   = (tt < 108) ? tt % 9 : (tt - 108);
        int ktl  = (cc < 12) ? kk : ((kk < 2) ? kk : 8);
        int n = nt * 32 + (lane & 31);
        int khalf = lane >> 5;
        if (ktl < 8) {
            int p = cc * 16 + ktl * 2 + khalf;       // always < P_
            const float4* src = (const float4*)(w1s + (size_t)n * 1568 + (size_t)p * 8);
            cvt8(src[0], src[1], ov.u);
        } else {
            int p0 = cc * 16 + khalf * 8;
            if (p0 + 7 < P_) {
                const float4* src = (const float4*)(w1b + (size_t)n * 196 + p0);
                cvt8(src[0], src[1], ov.u);
            } else {
#pragma unroll
                for (int j = 0; j < 8; j++) {
                    int p = p0 + j;
                    float v = (p < P_) ? w1b[(size_t)n * 196 + p] : 0.f;
                    ov.u[j] = f2bf_rne(v);
                }
            }
        }
        *(short8*)&w1p[(size_t)g * 8] = ov.s8;
    } else {
        int g2 = g - PACK_G1;
        int lane = g2 & 63;
        int lin  = g2 >> 6;              // tt*NT2 + nt
        int nt   = lin % NT2;
        int tt   = lin / NT2;
        int cc   = tt / 9;
        int ktl  = tt % 9;
        int n = nt * 32 + (lane & 31);
        int khalf = lane >> 5;
        if (n < P_) {
            if (ktl < 8) {
                int s = cc * 16 + ktl * 2 + khalf;
                const float4* src = (const float4*)(w2s + (size_t)n * 3072 + (size_t)s * 8);
                cvt8(src[0], src[1], ov.u);
            } else {
                int s0 = cc * 16 + khalf * 8;
                const float4* src = (const float4*)(w2b + (size_t)n * 384 + s0);
                cvt8(src[0], src[1], ov.u);
            }
        } else {
#pragma unroll
            for (int j = 0; j < 8; j++) ov.u[j] = f2bf_rne(0.f);
        }
        *(short8*)&w2p[(size_t)g2 * 8] = ov.s8;
    }
}

// frag LDS tile: [rt 3][khalf 2][col 32][8] = 1536 ushort; 9 tiles/buf.
#define TS_  1536
#define FB_  (9 * TS_)   // 13824 ushort per buffer

// R11: R4 structure + weight prefetch depth 3 (wbuf[3]): a weight fragment
// is now loaded ~3 kk (~240 cyc of MFMA issue) before use, covering L2-hit
// latency (~200-250 cyc) instead of depth-2's ~160 cyc.

// fc1: D[n][r] = W1 * act(x)^T; writes h1t[n][r].
__global__ __launch_bounds__(256, 2)
void fc1_kernel(const float* __restrict__ x,
                const unsigned short* __restrict__ w1p,
                const float* __restrict__ b1,
                unsigned short* __restrict__ h1t) {
    __shared__ __align__(16) unsigned short frag[2 * FB_];
    int blk = blockIdx.x;
    int tid = threadIdx.x;
    int b   = blk >> 3;
    int c0  = (blk & 7) * RT_;
    const float* xb = x + (size_t)b * (P_ * C_);

    int colA = tid & 63, scA = tid >> 6;
    int colB = 64 + (tid & 31), scB = tid >> 5;
    int pbase_rbfA  = ((colA >> 5) << 9) + (colA & 31) * 8;
    int pbase_rbfB  = 1024 + (colB & 31) * 8;
    int pbase_siluA = 8 * TS_ + ((colA >> 5) << 9) + ((scA >> 1) << 8) + (colA & 31) * 8 + (scA & 1) * 4;
    int pbase_siluB = 8 * TS_ + 1024 + ((scB >> 2) << 8) + (colB & 31) * 8 + (scB & 3) * 2;

    int wave = tid >> 6, lane = tid & 63;
    int l31 = lane & 31, half = lane >> 5;
    int nt0 = wave * 3;

    f32x16 acc[3][3];   // [rt][nt]
#pragma unroll
    for (int rt = 0; rt < 3; rt++)
#pragma unroll
        for (int nt = 0; nt < 3; nt++)
#pragma unroll
            for (int i = 0; i < 16; i++) acc[rt][nt][i] = 0.f;

    const short8* wp = (const short8*)w1p;
    short8 wbuf[3][3];

    auto wload = [&](int d, const short8* wt0, int kk) {
        const short8* wt = wt0 + (size_t)kk * (NT1 * 64);
        wbuf[d][0] = wt[0]; wbuf[d][1] = wt[64]; wbuf[d][2] = wt[128];
    };
    auto do_mfma = [&](short8 w0, short8 w1, short8 w2,
                       short8 a0, short8 a1, short8 a2) {
        acc[0][0] = MFMA(w0, a0, acc[0][0]); acc[1][0] = MFMA(w0, a1, acc[1][0]); acc[2][0] = MFMA(w0, a2, acc[2][0]);
        acc[0][1] = MFMA(w1, a0, acc[0][1]); acc[1][1] = MFMA(w1, a1, acc[1][1]); acc[2][1] = MFMA(w1, a2, acc[2][1]);
        acc[0][2] = MFMA(w2, a0, acc[0][2]); acc[1][2] = MFMA(w2, a1, acc[1][2]); acc[2][2] = MFMA(w2, a2, acc[2][2]);
    };
    auto produce = [&](int fb, const float (&ra)[4], const float (&rb2)[2]) {
#pragma unroll
        for (int i = 0; i < 4; i++) {
            int sl = scA * 4 + i;
            *(short8*)&frag[fb + (sl >> 1) * TS_ + ((sl & 1) << 8) + pbase_rbfA] = rbf8(ra[i]);
        }
#pragma unroll
        for (int i = 0; i < 2; i++) {
            int sl = scB * 2 + i;
            *(short8*)&frag[fb + (sl >> 1) * TS_ + ((sl & 1) << 8) + pbase_rbfB] = rbf8(rb2[i]);
        }
        uint2 sv;
        sv.x = silu2(ra[0], ra[1]);
        sv.y = silu2(ra[2], ra[3]);
        *(uint2*)&frag[fb + pbase_siluA] = sv;
        *(unsigned int*)&frag[fb + pbase_siluB] = silu2(rb2[0], rb2[1]);
    };
    auto body = [&](int cc, const float (&rbPA)[4], const float (&rbPB)[2],
                    float (&rbLA)[4], float (&rbLB)[2]) {
        const short8* wt0 = wp + ((size_t)(cc * 9) * NT1 + nt0) * 64 + lane;
        wload(0, wt0, 0); wload(1, wt0, 1); wload(2, wt0, 2);
        int fbP = ((cc + 1) & 1) * FB_;
        const unsigned short* fg = &frag[(cc & 1) * FB_];
        short8 a0 = *(const short8*)&fg[lane * 8];
        short8 a1 = *(const short8*)&fg[512 + lane * 8];
        short8 a2 = *(const short8*)&fg[1024 + lane * 8];
#pragma unroll
        for (int kk = 0; kk < 9; kk++) {
            short8 na0, na1, na2;
            if (kk < 8) {
                na0 = *(const short8*)&fg[(kk + 1) * TS_ + lane * 8];
                na1 = *(const short8*)&fg[(kk + 1) * TS_ + 512 + lane * 8];
                na2 = *(const short8*)&fg[(kk + 1) * TS_ + 1024 + lane * 8];
            }
            short8 w0 = wbuf[kk % 3][0], w1 = wbuf[kk % 3][1], w2 = wbuf[kk % 3][2];
            if (kk < 6) wload(kk % 3, wt0, kk + 3);
            if (kk < 4) {
                int sl = scA * 4 + kk;
                *(short8*)&frag[fbP + (sl >> 1) * TS_ + ((sl & 1) << 8) + pbase_rbfA] = rbf8(rbPA[kk]);
            } else if (kk == 4) {
#pragma unroll
                for (int i = 0; i < 2; i++) {
                    int sl = scB * 2 + i;
                    *(short8*)&frag[fbP + (sl >> 1) * TS_ + ((sl & 1) << 8) + pbase_rbfB] = rbf8(rbPB[i]);
                }
            } else if (kk == 5) {
                uint2 sv;
                sv.x = silu2(rbPA[0], rbPA[1]);
                sv.y = silu2(rbPA[2], rbPA[3]);
                *(uint2*)&frag[fbP + pbase_siluA] = sv;
                *(unsigned int*)&frag[fbP + pbase_siluB] = silu2(rbPB[0], rbPB[1]);
            } else if (kk == 6) {
#pragma unroll
                for (int i = 0; i < 2; i++) {
                    int p = (cc + 2) * 16 + scA * 4 + i;
                    p = (p < P_) ? p : (P_ - 1);
                    rbLA[i] = xb[(size_t)p * C_ + c0 + colA];
                }
            } else if (kk == 7) {
#pragma unroll
                for (int i = 2; i < 4; i++) {
                    int p = (cc + 2) * 16 + scA * 4 + i;
                    p = (p < P_) ? p : (P_ - 1);
                    rbLA[i] = xb[(size_t)p * C_ + c0 + colA];
                }
            } else {
#pragma unroll
                for (int i = 0; i < 2; i++) {
                    int p = (cc + 2) * 16 + scB * 2 + i;
                    p = (p < P_) ? p : (P_ - 1);
                    rbLB[i] = xb[(size_t)p * C_ + c0 + colB];
                }
            }
            do_mfma(w0, w1, w2, a0, a1, a2);
            if (kk < 8) { a0 = na0; a1 = na1; a2 = na2; }
        }
        block_sync_lds();
    };

    float rbA_A[4], rbB_A[4], rbA_B[2], rbB_B[2];
#pragma unroll
    for (int i = 0; i < 4; i++) {
        rbA_A[i] = xb[(size_t)(scA * 4 + i) * C_ + c0 + colA];
        rbB_A[i] = xb[(size_t)(16 + scA * 4 + i) * C_ + c0 + colA];
    }
#pragma unroll
    for (int i = 0; i < 2; i++) {
        rbA_B[i] = xb[(size_t)(scB * 2 + i) * C_ + c0 + colB];
        rbB_B[i] = xb[(size_t)(16 + scB * 2 + i) * C_ + c0 + colB];
    }
    produce(0, rbA_A, rbA_B);   // chunk 0 -> frag[0]
    block_sync_lds();

    for (int c2 = 0; c2 < 6; c2++) {          // chunks 0..11
        body(2 * c2,     rbB_A, rbB_B, rbA_A, rbA_B);
        body(2 * c2 + 1, rbA_A, rbA_B, rbB_A, rbB_B);
    }
    // tail: consume chunk 12 (tiles ktl {0,1,8}; weights linear 108..110)
    {
        const short8* wt0 = wp + ((size_t)108 * NT1 + nt0) * 64 + lane;
        wload(0, wt0, 0); wload(1, wt0, 1); wload(2, wt0, 2);
        const unsigned short* fg = &frag[0];  // chunk 12 parity 0
#pragma unroll
        for (int kk = 0; kk < 3; kk++) {
            int ktl = (kk < 2) ? kk : 8;
            short8 a0 = *(const short8*)&fg[ktl * TS_ + lane * 8];
            short8 a1 = *(const short8*)&fg[ktl * TS_ + 512 + lane * 8];
            short8 a2 = *(const short8*)&fg[ktl * TS_ + 1024 + lane * 8];
            do_mfma(wbuf[kk][0], wbuf[kk][1], wbuf[kk][2], a0, a1, a2);
        }
    }

    // epilogue: h1t[n][r]
#pragma unroll
    for (int nt = 0; nt < 3; nt++) {
        int n0 = (nt0 + nt) * 32 + 4 * half;
#pragma unroll
        for (int reg = 0; reg < 16; reg++) {
            int n = n0 + (reg & 3) + 8 * (reg >> 2);
            float bv = b1[n];
#pragma unroll
            for (int rt = 0; rt < 3; rt++) {
                h1t[(size_t)n * M_ + blk * RT_ + rt * 32 + l31] = f2bf_rne(acc[rt][nt][reg] + bv);
            }
        }
    }
}

// fc2: D[p][r] = W2 * act(h1)^T; out = D + b2 + x.
__global__ __launch_bounds__(256, 2)
void fc2_kernel(const unsigned short* __restrict__ h1t,
                const unsigned short* __restrict__ w2p,
                const float* __restrict__ b2,
                const float* __restrict__ x,
                float* __restrict__ out) {
    __shared__ __align__(16) unsigned short frag[2 * FB_];
    int blk = blockIdx.x;
    int tid = threadIdx.x;
    int rbase = blk * RT_;

    int colA = tid & 63, scA = tid >> 6;
    int colB = 64 + (tid & 31), scB = tid >> 5;
    int pbase_rbfA  = ((colA >> 5) << 9) + (colA & 31) * 8;
    int pbase_rbfB  = 1024 + (colB & 31) * 8;
    int pbase_siluA = 8 * TS_ + ((colA >> 5) << 9) + ((scA >> 1) << 8) + (colA & 31) * 8 + (scA & 1) * 4;
    int pbase_siluB = 8 * TS_ + 1024 + ((scB >> 2) << 8) + (colB & 31) * 8 + (scB & 3) * 2;

    int wave = tid >> 6, lane = tid & 63;
    int l31 = lane & 31, half = lane >> 5;
    int nt0 = wave * 2;
    int ntn = (wave < 3) ? 2 : 1;
    int off1 = (ntn > 1) ? 64 : 0;           // wave 3 dups its tile (discarded)

    f32x16 acc[3][2];   // [rt][nt]
#pragma unroll
    for (int rt = 0; rt < 3; rt++)
#pragma unroll
        for (int nt = 0; nt < 2; nt++)
#pragma unroll
            for (int i = 0; i < 16; i++) acc[rt][nt][i] = 0.f;

    const short8* wp = (const short8*)w2p;
    short8 wbuf[3][2];

    auto wload = [&](int d, const short8* wt0, int kk) {
        const short8* wt = wt0 + (size_t)kk * (NT2 * 64);
        wbuf[d][0] = wt[0]; wbuf[d][1] = wt[off1];
    };
    auto do_mfma = [&](short8 w0, short8 w1, short8 a0, short8 a1, short8 a2) {
        acc[0][0] = MFMA(w0, a0, acc[0][0]); acc[1][0] = MFMA(w0, a1, acc[1][0]); acc[2][0] = MFMA(w0, a2, acc[2][0]);
        if (ntn == 2) {
            acc[0][1] = MFMA(w1, a0, acc[0][1]); acc[1][1] = MFMA(w1, a1, acc[1][1]); acc[2][1] = MFMA(w1, a2, acc[2][1]);
        }
    };
    auto produce = [&](int fb, const unsigned short (&ra)[4], const unsigned short (&rb2)[2]) {
        float v0 = bf2f(ra[0]), v1 = bf2f(ra[1]), v2 = bf2f(ra[2]), v3 = bf2f(ra[3]);
        float u0 = bf2f(rb2[0]), u1 = bf2f(rb2[1]);
        float vv[4] = {v0, v1, v2, v3};
#pragma unroll
        for (int i = 0; i < 4; i++) {
            int sl = scA * 4 + i;
            *(short8*)&frag[fb + (sl >> 1) * TS_ + ((sl & 1) << 8) + pbase_rbfA] = rbf8(vv[i]);
        }
        float uu[2] = {u0, u1};
#pragma unroll
        for (int i = 0; i < 2; i++) {
            int sl = scB * 2 + i;
            *(short8*)&frag[fb + (sl >> 1) * TS_ + ((sl & 1) << 8) + pbase_rbfB] = rbf8(uu[i]);
        }
        uint2 sv;
        sv.x = silu2(v0, v1);
        sv.y = silu2(v2, v3);
        *(uint2*)&frag[fb + pbase_siluA] = sv;
        *(unsigned int*)&frag[fb + pbase_siluB] = silu2(u0, u1);
    };
    auto body = [&](int cc, const unsigned short (&rbPA)[4], const unsigned short (&rbPB)[2],
                    unsigned short (&rbLA)[4], unsigned short (&rbLB)[2]) {
        bool doProd = (cc + 1 < NC2);
        const short8* wt0 = wp + ((size_t)(cc * 9) * NT2 + nt0) * 64 + lane;
        wload(0, wt0, 0); wload(1, wt0, 1); wload(2, wt0, 2);
        int fbP = ((cc + 1) & 1) * FB_;
        const unsigned short* fg = &frag[(cc & 1) * FB_];
        short8 a0 = *(const short8*)&fg[lane * 8];
        short8 a1 = *(const short8*)&fg[512 + lane * 8];
        short8 a2 = *(const short8*)&fg[1024 + lane * 8];
#pragma unroll
        for (int kk = 0; kk < 9; kk++) {
            short8 na0, na1, na2;
            if (kk < 8) {
                na0 = *(const short8*)&fg[(kk + 1) * TS_ + lane * 8];
                na1 = *(const short8*)&fg[(kk + 1) * TS_ + 512 + lane * 8];
                na2 = *(const short8*)&fg[(kk + 1) * TS_ + 1024 + lane * 8];
            }
            short8 w0 = wbuf[kk % 3][0], w1 = wbuf[kk % 3][1];
            if (kk < 6) wload(kk % 3, wt0, kk + 3);
            if (kk < 4) {
                if (doProd) {
                    int sl = scA * 4 + kk;
                    *(short8*)&frag[fbP + (sl >> 1) * TS_ + ((sl & 1) << 8) + pbase_rbfA] =
                        rbf8(bf2f(rbPA[kk]));
                }
            } else if (kk == 4) {
                if (doProd) {
#pragma unroll
                    for (int i = 0; i < 2; i++) {
                        int sl = scB * 2 + i;
                        *(short8*)&frag[fbP + (sl >> 1) * TS_ + ((sl & 1) << 8) + pbase_rbfB] =
                            rbf8(bf2f(rbPB[i]));
                    }
                }
            } else if (kk == 5) {
                if (doProd) {
                    uint2 sv;
                    sv.x = silu2(bf2f(rbPA[0]), bf2f(rbPA[1]));
                    sv.y = silu2(bf2f(rbPA[2]), bf2f(rbPA[3]));
                    *(uint2*)&frag[fbP + pbase_siluA] = sv;
                    *(unsigned int*)&frag[fbP + pbase_siluB] = silu2(bf2f(rbPB[0]), bf2f(rbPB[1]));
                }
            } else if (kk == 6) {
#pragma unroll
                for (int i = 0; i < 2; i++) {
                    int s = (cc + 2) * 16 + scA * 4 + i;
                    s = (s < HS_) ? s : (HS_ - 1);
                    rbLA[i] = h1t[(size_t)s * M_ + rbase + colA];
                }
            } else if (kk == 7) {
#pragma unroll
                for (int i = 2; i < 4; i++) {
                    int s = (cc + 2) * 16 + scA * 4 + i;
                    s = (s < HS_) ? s : (HS_ - 1);
                    rbLA[i] = h1t[(size_t)s * M_ + rbase + colA];
                }
            } else {
#pragma unroll
                for (int i = 0; i < 2; i++) {
                    int s = (cc + 2) * 16 + scB * 2 + i;
                    s = (s < HS_) ? s : (HS_ - 1);
                    rbLB[i] = h1t[(size_t)s * M_ + rbase + colB];
                }
            }
            do_mfma(w0, w1, a0, a1, a2);
            if (kk < 8) { a0 = na0; a1 = na1; a2 = na2; }
        }
        block_sync_lds();
    };

    unsigned short rbA_A[4], rbB_A[4], rbA_B[2], rbB_B[2];
#pragma unroll
    for (int i = 0; i < 4; i++) {
        rbA_A[i] = h1t[(size_t)(scA * 4 + i) * M_ + rbase + colA];
        rbB_A[i] = h1t[(size_t)(16 + scA * 4 + i) * M_ + rbase + colA];
    }
#pragma unroll
    for (int i = 0; i < 2; i++) {
        rbA_B[i] = h1t[(size_t)(scB * 2 + i) * M_ + rbase + colB];
        rbB_B[i] = h1t[(size_t)(16 + scB * 2 + i) * M_ + rbase + colB];
    }
    produce(0, rbA_A, rbA_B);   // chunk 0 -> frag[0]
    block_sync_lds();

    for (int c2 = 0; c2 < 12; c2++) {        // chunks 0..23
        body(2 * c2,     rbB_A, rbB_B, rbA_A, rbA_B);
        body(2 * c2 + 1, rbA_A, rbA_B, rbB_A, rbB_B);
    }

    // epilogue: out[b,p,c] = acc + b2[p] + x[b,p,c]
    int b = blk >> 3;
    int c0 = (blk & 7) * RT_;
#pragma unroll
    for (int nt = 0; nt < 2; nt++) {
        if (nt < ntn) {
            int p0 = (nt0 + nt) * 32 + 4 * half;
#pragma unroll
            for (int reg = 0; reg < 16; reg++) {
                int p = p0 + (reg & 3) + 8 * (reg >> 2);
                if (p < P_) {
                    float bv = b2[p];
#pragma unroll
                    for (int rt = 0; rt < 3; rt++) {
                        size_t off = ((size_t)b * P_ + p) * C_ + c0 + rt * 32 + l31;
                        out[off] = acc[rt][nt][reg] + bv + x[off];
                    }
                }
            }
        }
    }
}

extern "C" void kernel_launch(void* const* d_in, const int* in_sizes, int n_in,
                              void* d_out, int out_size, void* d_ws, size_t ws_size,
                              hipStream_t stream) {
    const float* x   = (const float*)d_in[0];
    const float* w1s = (const float*)d_in[1];
    const float* w1b = (const float*)d_in[2];
    const float* b1  = (const float*)d_in[3];
    const float* w2s = (const float*)d_in[4];
    const float* w2b = (const float*)d_in[5];
    const float* b2  = (const float*)d_in[6];
    float* out = (float*)d_out;

    unsigned short* h1t = (unsigned short*)d_ws;            // 37.75 MB bf16 [n][r]
    unsigned short* w1p = h1t + H1_ELEMS;
    unsigned short* w2p = w1p + W1P_ELEMS;                  // total ~40.7 MB

    int pack_blocks = (PACK_G + 255) / 256;                 // 711
    pack_w_kernel<<<pack_blocks, 256, 0, stream>>>(w1s, w1b, w2s, w2b, w1p, w2p);
    fc1_kernel<<<NB_, 256, 0, stream>>>(x, w1p, b1, h1t);
    fc2_kernel<<<NB_, 256, 0, stream>>>(h1t, w2p, b2, x, out);
}